// Round 4
// baseline (185.718 us; speedup 1.0000x reference)
//
#include <hip/hip_runtime.h>

#define LOG_2PI_F 1.8378770664093453f

constexpr int BC = 1024, CC = 16, PV = 16, LV = 64, BB = 4, NROW = 64;
constexpr int CH = (PV + 1) * BC;
constexpr int SLAB = BB * CC * LV;           // 4096
constexpr int SLABTOT = 2 * SLAB + BB * CC;  // 8256
constexpr int NSLAB_SM = 32;

typedef __attribute__((ext_vector_type(4))) short short4v;
typedef __attribute__((ext_vector_type(8))) short short8v;
typedef __attribute__((ext_vector_type(16))) float f32x16;

union ABfrag { short8v v; short4v h[2]; unsigned short u[8]; };

__device__ __forceinline__ unsigned short f2bf(float f) {
  unsigned u = __float_as_uint(f);
  u += 0x7fffu + ((u >> 16) & 1u);  // RNE
  return (unsigned short)(u >> 16);
}

// One block per capsule i. 4 waves; wave w owns c = 4w..4w+3.
// Votes via v_mfma_f32_32x32x16_bf16: M=32 (2 batches x 16 rows), N=32 (l-half), K=16 (=P).
// A: m=lane&31, k=8*(lane>>5)+j ; B: n=lane&31, k=8*(lane>>5)+j
// C/D: col=lane&31, row=(reg&3)+8*(reg>>2)+4*(lane>>5)   [m74/m101 verified]
// W fragments live in REGISTERS (no cross-wave sharing -> no LDS round-trip).
template <int PASS, int STORE>
__global__ __launch_bounds__(256, 3) void em_sweep(
    const float* __restrict__ x, const float* __restrict__ W,
    const float* __restrict__ mu, const float* __restrict__ T,
    float* __restrict__ Spart, int nslab) {
  const int i = blockIdx.x, t = threadIdx.x;
  const int w = t >> 6, lane = t & 63;
  const int ln31 = lane & 31, h = lane >> 5;
  const int cbase = 4 * w;

  float* S1p = Spart + (size_t)(blockIdx.x % nslab) * SLABTOT;
  float* S2p = S1p + SLAB;
  float* Srp = S1p + 2 * SLAB;

  __shared__ __align__(16) unsigned short pbf[64][20];  // pitch 40B: <=2-way banks
  __shared__ float act_s[64];
  __shared__ float T_s[64];
  __shared__ float sr_s[64];
  __shared__ float sc_s[64][17];
  __shared__ float rh2[16][64];

  // ---- W -> bf16 fragments in registers ----
  // lane (ln31,h) of frag (cl_,lh) holds W[c=cbase+cl_][i][l=lh*32+ln31][8h..8h+7].
  // Per (cl_,lh) the wave reads a contiguous 2KB segment (64 lanes x 32B): coalesced.
  short8v wf[8];
#pragma unroll
  for (int cl_ = 0; cl_ < 4; ++cl_)
#pragma unroll
    for (int lh = 0; lh < 2; ++lh) {
      const float* src = W + ((size_t)(cbase + cl_) * BC + i) * 1024 +
                         (lh * 32 + ln31) * 16 + 8 * h;
      const float4 v0 = *reinterpret_cast<const float4*>(src);
      const float4 v1 = *reinterpret_cast<const float4*>(src + 4);
      ABfrag f;
      f.u[0] = f2bf(v0.x); f.u[1] = f2bf(v0.y);
      f.u[2] = f2bf(v0.z); f.u[3] = f2bf(v0.w);
      f.u[4] = f2bf(v1.x); f.u[5] = f2bf(v1.y);
      f.u[6] = f2bf(v1.z); f.u[7] = f2bf(v1.w);
      wf[cl_ * 2 + lh] = f.v;
    }

  // ---- stage pose -> bf16 LDS, act -> f32 ----
  {
    const int b = t >> 6, p = (t >> 2) & 15, q = t & 3;
    const float4 v = *reinterpret_cast<const float4*>(
        x + ((size_t)(b * CH + p * BC + i)) * 16 + 4 * q);
    pbf[b * 16 + 4 * q + 0][p] = f2bf(v.x);
    pbf[b * 16 + 4 * q + 1][p] = f2bf(v.y);
    pbf[b * 16 + 4 * q + 2][p] = f2bf(v.z);
    pbf[b * 16 + 4 * q + 3][p] = f2bf(v.w);
  }
  if (t < 64) {
    const int b = t >> 4, xy = t & 15;
    act_s[t] = x[((size_t)(b * CH + PV * BC + i)) * 16 + xy];
    if (PASS == 1) { T_s[t] = T[t]; sr_s[t] = 0.f; }
  }

  float mur[4][2][4];  // [c_local][lh][b], per-lane l = lh*32 + ln31
  if (PASS == 1) {
#pragma unroll
    for (int cl_ = 0; cl_ < 4; ++cl_)
#pragma unroll
      for (int lh = 0; lh < 2; ++lh)
#pragma unroll
        for (int b = 0; b < 4; ++b)
          mur[cl_][lh][b] = mu[(b * CC + cbase + cl_) * LV + lh * 32 + ln31];
  }
  __syncthreads();

  const f32x16 zero16 = {};

  if (PASS == 1) {
    // ---- phase A: scores ----
#pragma unroll
    for (int pair = 0; pair < 2; ++pair) {
      ABfrag A;
      {
        const int r = pair * 32 + ln31;
        A.h[0] = *reinterpret_cast<const short4v*>(&pbf[r][8 * h]);
        A.h[1] = *reinterpret_cast<const short4v*>(&pbf[r][8 * h + 4]);
      }
#pragma unroll
      for (int cl_ = 0; cl_ < 4; ++cl_) {
        float scv[16];
#pragma unroll
        for (int j = 0; j < 16; ++j) scv[j] = 0.f;
#pragma unroll
        for (int lh = 0; lh < 2; ++lh) {
          const f32x16 acc = __builtin_amdgcn_mfma_f32_32x32x16_bf16(
              A.v, wf[cl_ * 2 + lh], zero16, 0, 0, 0);
#pragma unroll
          for (int j = 0; j < 16; ++j) {
            const float d = acc[j] - mur[cl_][lh][pair * 2 + (j >> 3)];
            scv[j] = fmaf(d, d, scv[j]);
          }
        }
#pragma unroll
        for (int j = 0; j < 16; ++j) {  // sum over 32 cols (within half-wave)
          float v = scv[j];
          v += __shfl_xor(v, 1, 64);  v += __shfl_xor(v, 2, 64);
          v += __shfl_xor(v, 4, 64);  v += __shfl_xor(v, 8, 64);
          v += __shfl_xor(v, 16, 64);
          if (ln31 == 0)
            sc_s[pair * 32 + (j & 3) + 8 * (j >> 2) + 4 * h][cbase + cl_] = v;
        }
      }
    }
    __syncthreads();
    // ---- softmax over c (all 256 threads, 4x redundant rows) ----
    {
      const int r = t & 63, cq = t >> 6, b = r >> 4;
      float s[16];
#pragma unroll
      for (int cc = 0; cc < 16; ++cc) s[cc] = T_s[b * CC + cc] - sc_s[r][cc];
      float m = s[0];
#pragma unroll
      for (int cc = 1; cc < 16; ++cc) m = fmaxf(m, s[cc]);
      float den = 0.f;
#pragma unroll
      for (int cc = 0; cc < 16; ++cc) { s[cc] = __expf(s[cc] - m); den += s[cc]; }
      const float a = act_s[r] / den;
#pragma unroll
      for (int k = 0; k < 4; ++k) {
        const int cc = 4 * cq + k;
        const float rh = fmaxf(s[cc] * a, 0.01f);
        rh2[cc][r] = rh;
        atomicAdd(&sr_s[b * CC + cc], rh);
      }
    }
    __syncthreads();
  }

  // ---- phase B: S1/S2 ----
#pragma unroll
  for (int pair = 0; pair < 2; ++pair) {
    ABfrag A;
    {
      const int r = pair * 32 + ln31;
      A.h[0] = *reinterpret_cast<const short4v*>(&pbf[r][8 * h]);
      A.h[1] = *reinterpret_cast<const short4v*>(&pbf[r][8 * h + 4]);
    }
    float p1[8][2] = {}, p2[8][2] = {};  // [tile8][batch-half]
#pragma unroll
    for (int cl_ = 0; cl_ < 4; ++cl_) {
      float rq[16];
      if (PASS == 1) {
#pragma unroll
        for (int g = 0; g < 4; ++g) {
          const float4 v = *reinterpret_cast<const float4*>(
              &rh2[cbase + cl_][pair * 32 + 8 * g + 4 * h]);
          rq[4 * g + 0] = v.x; rq[4 * g + 1] = v.y;
          rq[4 * g + 2] = v.z; rq[4 * g + 3] = v.w;
        }
      } else {
#pragma unroll
        for (int g = 0; g < 4; ++g) {
          const float4 v = *reinterpret_cast<const float4*>(
              &act_s[pair * 32 + 8 * g + 4 * h]);
          rq[4 * g + 0] = fmaxf(v.x * 0.0625f, 0.01f);
          rq[4 * g + 1] = fmaxf(v.y * 0.0625f, 0.01f);
          rq[4 * g + 2] = fmaxf(v.z * 0.0625f, 0.01f);
          rq[4 * g + 3] = fmaxf(v.w * 0.0625f, 0.01f);
        }
      }
#pragma unroll
      for (int lh = 0; lh < 2; ++lh) {
        const f32x16 acc = __builtin_amdgcn_mfma_f32_32x32x16_bf16(
            A.v, wf[cl_ * 2 + lh], zero16, 0, 0, 0);
        const int t8 = cl_ * 2 + lh;
#pragma unroll
        for (int j = 0; j < 16; ++j) {
          const float v = acc[j];
          const float rv = rq[j] * v;
          p1[t8][j >> 3] += rv;
          p2[t8][j >> 3] = fmaf(rv, v, p2[t8][j >> 3]);
        }
      }
    }
#pragma unroll
    for (int t8 = 0; t8 < 8; ++t8)
#pragma unroll
      for (int bh = 0; bh < 2; ++bh) {
        float v1 = p1[t8][bh]; v1 += __shfl_xor(v1, 32, 64);
        float v2 = p2[t8][bh]; v2 += __shfl_xor(v2, 32, 64);
        const int b = pair * 2 + bh, c = cbase + (t8 >> 1);
        const int idx = (b * CC + c) * LV + (t8 & 1) * 32 + ln31;
        if (STORE) {
          if (h == 0) { S1p[idx] = v1; S2p[idx] = v2; }
        } else if (h == 0) {
          atomicAdd(&S1p[idx], v1); atomicAdd(&S2p[idx], v2);
        }
      }
  }

  // ---- Sr ----
  if (PASS == 1) {
    if (t < 64) { if (STORE) Srp[t] = sr_s[t]; else atomicAdd(&Srp[t], sr_s[t]); }
  } else {
    if (t < 64) {
      const int b = t >> 4;
      float s = 0.f;
#pragma unroll
      for (int xy = 0; xy < 16; ++xy) s += fmaxf(act_s[b * 16 + xy] * 0.0625f, 0.01f);
      if (STORE) Srp[t] = s; else atomicAdd(&Srp[t], s);
    }
  }
}

__global__ void reduce_slabs(const float* __restrict__ Spart, float* __restrict__ Sred,
                             int nslab, int chunk) {
  const int idx = blockIdx.x * 256 + threadIdx.x;
  if (idx >= SLABTOT) return;
  const int s0 = blockIdx.y * chunk;
  const int s1 = min(s0 + chunk, nslab);
  float a = 0.f;
#pragma unroll 8
  for (int s = s0; s < s1; s++) a += Spart[(size_t)s * SLABTOT + idx];
  atomicAdd(&Sred[idx], a);
}

template <int FINAL>
__global__ void stats_post(const float* __restrict__ Sred,
                           const float* __restrict__ beta_v,
                           const float* __restrict__ beta_a,
                           const float* __restrict__ lam,
                           float* __restrict__ mu_out, float* __restrict__ T_out,
                           float* __restrict__ out) {
  const int t = threadIdx.x;
  if (t >= 64) return;
  const int b = t >> 4, c = t & 15;
  const float* S1 = Sred;
  const float* S2 = Sred + SLAB;
  const float sr = Sred[2 * SLAB + b * CC + c];
  const float inv = 1.f / sr;
  const float bv = beta_v[0];
  float csum = 0.f, lsum = 0.f;
  for (int l = 0; l < LV; l++) {
    const int idx = (b * CC + c) * LV + l;
    const float m = S1[idx] * inv;
    float s2 = S2[idx] * inv - m * m;
    s2 = fmaxf(s2, 0.01f);
    const float ls = logf(s2);
    csum += bv + ls;
    lsum += ls;
    if (FINAL) out[(size_t)b * 1040 + c * LV + l] = m;
    else mu_out[idx] = m;
  }
  const float z = lam[0] * (beta_a[c] - csum * sr);
  const float ac = 1.f / (1.f + expf(-z));
  if (FINAL) out[(size_t)b * 1040 + 1024 + c] = ac;
  else T_out[b * CC + c] = logf(ac) - 0.5f * (64.f * LOG_2PI_F + lsum);
}

extern "C" void kernel_launch(void* const* d_in, const int* in_sizes, int n_in,
                              void* d_out, int out_size, void* d_ws, size_t ws_size,
                              hipStream_t stream) {
  const float* x = (const float*)d_in[0];
  const float* W = (const float*)d_in[1];
  const float* beta_v = (const float*)d_in[2];
  const float* beta_a = (const float*)d_in[3];
  const float* lam = (const float*)d_in[4];
  float* out = (float*)d_out;

  const size_t need = ((size_t)BC * SLABTOT + SLABTOT + SLAB + 64) * sizeof(float);
  const int nslab = (ws_size >= need) ? BC : NSLAB_SM;
  const bool store = (nslab == BC);

  float* Spart = (float*)d_ws;
  float* Sred = Spart + (size_t)nslab * SLABTOT;
  float* muW = Sred + SLABTOT;
  float* Tw = muW + SLAB;

  const int chunk = 32;
  const dim3 rgrid((SLABTOT + 255) / 256, (nslab + chunk - 1) / chunk);

  // ---- pass 0 ----
  if (!store) hipMemsetAsync(Spart, 0, (size_t)nslab * SLABTOT * sizeof(float), stream);
  hipMemsetAsync(Sred, 0, SLABTOT * sizeof(float), stream);
  if (store) em_sweep<0, 1><<<dim3(BC), dim3(256), 0, stream>>>(x, W, nullptr, nullptr, Spart, nslab);
  else       em_sweep<0, 0><<<dim3(BC), dim3(256), 0, stream>>>(x, W, nullptr, nullptr, Spart, nslab);
  reduce_slabs<<<rgrid, dim3(256), 0, stream>>>(Spart, Sred, nslab, chunk);
  stats_post<0><<<dim3(1), dim3(64), 0, stream>>>(Sred, beta_v, beta_a, lam, muW, Tw, nullptr);

  // ---- pass 1 ----
  if (!store) hipMemsetAsync(Spart, 0, (size_t)nslab * SLABTOT * sizeof(float), stream);
  hipMemsetAsync(Sred, 0, SLABTOT * sizeof(float), stream);
  if (store) em_sweep<1, 1><<<dim3(BC), dim3(256), 0, stream>>>(x, W, muW, Tw, Spart, nslab);
  else       em_sweep<1, 0><<<dim3(BC), dim3(256), 0, stream>>>(x, W, muW, Tw, Spart, nslab);
  reduce_slabs<<<rgrid, dim3(256), 0, stream>>>(Spart, Sred, nslab, chunk);
  stats_post<1><<<dim3(1), dim3(64), 0, stream>>>(Sred, beta_v, beta_a, lam, nullptr, nullptr, out);
}

// Round 5
// 116.376 us; speedup vs baseline: 1.5958x; 1.5958x over previous
//
#include <hip/hip_runtime.h>

#define LOG_2PI_F 1.8378770664093453f

constexpr int BC = 1024, CC = 16, PV = 16, LV = 64, BB = 4, NROW = 64;
constexpr int CH = (PV + 1) * BC;
constexpr int SLAB = BB * CC * LV;           // 4096
constexpr int SLABTOT = 2 * SLAB + BB * CC;  // 8256
constexpr int NSLAB_SM = 32;

typedef __attribute__((ext_vector_type(4))) short short4v;
typedef __attribute__((ext_vector_type(8))) short short8v;
typedef __attribute__((ext_vector_type(16))) float f32x16;
typedef __attribute__((ext_vector_type(4))) unsigned short us4;

union ABfrag { short8v v; short4v h[2]; unsigned short u[8]; };

__device__ __forceinline__ unsigned short f2bf(float f) {
  unsigned u = __float_as_uint(f);
  u += 0x7fffu + ((u >> 16) & 1u);  // RNE
  return (unsigned short)(u >> 16);
}

// One block per capsule i. 8 waves; wave w owns c = 2w..2w+1.
// Votes via v_mfma_f32_32x32x16_bf16: M=32 (2 batches x 16 rows), N=32 (l-half), K=16 (=P).
// A: m=lane&31, k=8*(lane>>5)+j ; B: n=lane&31, k=8*(lane>>5)+j
// C/D: col=lane&31, row=(reg&3)+8*(reg>>2)+4*(lane>>5)   [m74/m101 verified]
// W staged bf16 in LDS, pitch 20 ushorts (40B) -> <=2-way banks (free, m136).
template <int PASS, int STORE>
__global__ __launch_bounds__(512, 4) void em_sweep(
    const float* __restrict__ x, const float* __restrict__ W,
    const float* __restrict__ mu, const float* __restrict__ T,
    float* __restrict__ Spart, int nslab) {
  const int i = blockIdx.x, t = threadIdx.x;
  const int w = t >> 6, lane = t & 63;
  const int ln31 = lane & 31, h = lane >> 5;
  const int cbase = 2 * w;

  float* S1p = Spart + (size_t)(blockIdx.x % nslab) * SLABTOT;
  float* S2p = S1p + SLAB;
  float* Srp = S1p + 2 * SLAB;

  __shared__ __align__(16) unsigned short Wbf[1024][20];
  __shared__ __align__(16) unsigned short pbf[64][20];
  __shared__ float act_s[64];
  __shared__ float T_s[64];
  __shared__ float sr_s[64];
  __shared__ float sc_s[64][17];
  __shared__ float rh2[16][64];

  // ---- stage W -> bf16 LDS (coalesced 64B/thread runs) ----
#pragma unroll
  for (int rep = 0; rep < 2; ++rep) {
    const int cl = rep * 512 + t;
    const int c = cl >> 6, l = cl & 63;
    const float* src = W + ((size_t)c * BC + i) * 1024 + l * 16;
#pragma unroll
    for (int q = 0; q < 4; ++q) {
      const float4 v = *reinterpret_cast<const float4*>(src + 4 * q);
      us4 u;
      u[0] = f2bf(v.x); u[1] = f2bf(v.y); u[2] = f2bf(v.z); u[3] = f2bf(v.w);
      *reinterpret_cast<us4*>(&Wbf[cl][4 * q]) = u;
    }
  }
  // ---- stage pose -> bf16 LDS, act -> f32 ----
  if (t < 256) {
    const int b = t >> 6, p = (t >> 2) & 15, q = t & 3;
    const float4 v = *reinterpret_cast<const float4*>(
        x + ((size_t)(b * CH + p * BC + i)) * 16 + 4 * q);
    pbf[b * 16 + 4 * q + 0][p] = f2bf(v.x);
    pbf[b * 16 + 4 * q + 1][p] = f2bf(v.y);
    pbf[b * 16 + 4 * q + 2][p] = f2bf(v.z);
    pbf[b * 16 + 4 * q + 3][p] = f2bf(v.w);
  }
  if (t < 64) {
    const int b = t >> 4, xy = t & 15;
    act_s[t] = x[((size_t)(b * CH + PV * BC + i)) * 16 + xy];
    if (PASS == 1) { T_s[t] = T[t]; sr_s[t] = 0.f; }
  }

  float mur[2][2][4];  // [c_local][lh][b], per-lane l = lh*32 + ln31
  if (PASS == 1) {
#pragma unroll
    for (int cl_ = 0; cl_ < 2; ++cl_)
#pragma unroll
      for (int lh = 0; lh < 2; ++lh)
#pragma unroll
        for (int b = 0; b < 4; ++b)
          mur[cl_][lh][b] = mu[(b * CC + cbase + cl_) * LV + lh * 32 + ln31];
  }
  __syncthreads();

  // ---- per-wave W fragments from LDS (reused across phases) ----
  short8v wf[4];
#pragma unroll
  for (int cl_ = 0; cl_ < 2; ++cl_)
#pragma unroll
    for (int lh = 0; lh < 2; ++lh) {
      const int cl = (cbase + cl_) * 64 + lh * 32 + ln31;
      ABfrag f;
      f.h[0] = *reinterpret_cast<const short4v*>(&Wbf[cl][8 * h]);
      f.h[1] = *reinterpret_cast<const short4v*>(&Wbf[cl][8 * h + 4]);
      wf[cl_ * 2 + lh] = f.v;
    }

  const f32x16 zero16 = {};

  if (PASS == 1) {
    // ---- phase A: scores ----
#pragma unroll
    for (int pair = 0; pair < 2; ++pair) {
      ABfrag A;
      {
        const int r = pair * 32 + ln31;
        A.h[0] = *reinterpret_cast<const short4v*>(&pbf[r][8 * h]);
        A.h[1] = *reinterpret_cast<const short4v*>(&pbf[r][8 * h + 4]);
      }
#pragma unroll
      for (int cl_ = 0; cl_ < 2; ++cl_) {
        float scv[16];
#pragma unroll
        for (int j = 0; j < 16; ++j) scv[j] = 0.f;
#pragma unroll
        for (int lh = 0; lh < 2; ++lh) {
          const f32x16 acc = __builtin_amdgcn_mfma_f32_32x32x16_bf16(
              A.v, wf[cl_ * 2 + lh], zero16, 0, 0, 0);
#pragma unroll
          for (int j = 0; j < 16; ++j) {
            const float d = acc[j] - mur[cl_][lh][pair * 2 + (j >> 3)];
            scv[j] = fmaf(d, d, scv[j]);
          }
        }
#pragma unroll
        for (int j = 0; j < 16; ++j) {  // sum over 32 cols (within half-wave)
          float v = scv[j];
          v += __shfl_xor(v, 1, 64);  v += __shfl_xor(v, 2, 64);
          v += __shfl_xor(v, 4, 64);  v += __shfl_xor(v, 8, 64);
          v += __shfl_xor(v, 16, 64);
          if (ln31 == 0)
            sc_s[pair * 32 + (j & 3) + 8 * (j >> 2) + 4 * h][cbase + cl_] = v;
        }
      }
    }
    __syncthreads();
    // ---- softmax over c (all 512 threads, 8x redundant rows) ----
    {
      const int r = t & 63, cq = t >> 6, b = r >> 4;
      float s[16];
#pragma unroll
      for (int cc = 0; cc < 16; ++cc) s[cc] = T_s[b * CC + cc] - sc_s[r][cc];
      float m = s[0];
#pragma unroll
      for (int cc = 1; cc < 16; ++cc) m = fmaxf(m, s[cc]);
      float den = 0.f;
#pragma unroll
      for (int cc = 0; cc < 16; ++cc) { s[cc] = __expf(s[cc] - m); den += s[cc]; }
      const float a = act_s[r] / den;
#pragma unroll
      for (int k = 0; k < 2; ++k) {
        const int cc = 2 * cq + k;
        const float rh = fmaxf(s[cc] * a, 0.01f);
        rh2[cc][r] = rh;
        atomicAdd(&sr_s[b * CC + cc], rh);
      }
    }
    __syncthreads();
  }

  // ---- phase B: S1/S2 ----
#pragma unroll
  for (int pair = 0; pair < 2; ++pair) {
    ABfrag A;
    {
      const int r = pair * 32 + ln31;
      A.h[0] = *reinterpret_cast<const short4v*>(&pbf[r][8 * h]);
      A.h[1] = *reinterpret_cast<const short4v*>(&pbf[r][8 * h + 4]);
    }
    float p1[4][2] = {}, p2[4][2] = {};  // [tile4][batch-half]
#pragma unroll
    for (int cl_ = 0; cl_ < 2; ++cl_) {
      float rq[16];
      if (PASS == 1) {
#pragma unroll
        for (int g = 0; g < 4; ++g) {
          const float4 v = *reinterpret_cast<const float4*>(
              &rh2[cbase + cl_][pair * 32 + 8 * g + 4 * h]);
          rq[4 * g + 0] = v.x; rq[4 * g + 1] = v.y;
          rq[4 * g + 2] = v.z; rq[4 * g + 3] = v.w;
        }
      } else {
#pragma unroll
        for (int g = 0; g < 4; ++g) {
          const float4 v = *reinterpret_cast<const float4*>(
              &act_s[pair * 32 + 8 * g + 4 * h]);
          rq[4 * g + 0] = fmaxf(v.x * 0.0625f, 0.01f);
          rq[4 * g + 1] = fmaxf(v.y * 0.0625f, 0.01f);
          rq[4 * g + 2] = fmaxf(v.z * 0.0625f, 0.01f);
          rq[4 * g + 3] = fmaxf(v.w * 0.0625f, 0.01f);
        }
      }
#pragma unroll
      for (int lh = 0; lh < 2; ++lh) {
        const f32x16 acc = __builtin_amdgcn_mfma_f32_32x32x16_bf16(
            A.v, wf[cl_ * 2 + lh], zero16, 0, 0, 0);
        const int t4 = cl_ * 2 + lh;
#pragma unroll
        for (int j = 0; j < 16; ++j) {
          const float v = acc[j];
          const float rv = rq[j] * v;
          p1[t4][j >> 3] += rv;
          p2[t4][j >> 3] = fmaf(rv, v, p2[t4][j >> 3]);
        }
      }
    }
#pragma unroll
    for (int t4 = 0; t4 < 4; ++t4)
#pragma unroll
      for (int bh = 0; bh < 2; ++bh) {
        float v1 = p1[t4][bh]; v1 += __shfl_xor(v1, 32, 64);
        float v2 = p2[t4][bh]; v2 += __shfl_xor(v2, 32, 64);
        const int b = pair * 2 + bh, c = cbase + (t4 >> 1);
        const int idx = (b * CC + c) * LV + (t4 & 1) * 32 + ln31;
        if (STORE) {
          if (h == 0) { S1p[idx] = v1; S2p[idx] = v2; }
        } else if (h == 0) {
          atomicAdd(&S1p[idx], v1); atomicAdd(&S2p[idx], v2);
        }
      }
  }

  // ---- Sr ----
  if (PASS == 1) {
    if (t < 64) { if (STORE) Srp[t] = sr_s[t]; else atomicAdd(&Srp[t], sr_s[t]); }
  } else {
    if (t < 64) {
      const int b = t >> 4;
      float s = 0.f;
#pragma unroll
      for (int xy = 0; xy < 16; ++xy) s += fmaxf(act_s[b * 16 + xy] * 0.0625f, 0.01f);
      if (STORE) Srp[t] = s; else atomicAdd(&Srp[t], s);
    }
  }
}

__global__ void reduce_slabs(const float* __restrict__ Spart, float* __restrict__ Sred,
                             int nslab, int chunk) {
  const int idx = blockIdx.x * 256 + threadIdx.x;
  if (idx >= SLABTOT) return;
  const int s0 = blockIdx.y * chunk;
  const int s1 = min(s0 + chunk, nslab);
  float a = 0.f;
#pragma unroll 8
  for (int s = s0; s < s1; s++) a += Spart[(size_t)s * SLABTOT + idx];
  atomicAdd(&Sred[idx], a);
}

template <int FINAL>
__global__ void stats_post(const float* __restrict__ Sred,
                           const float* __restrict__ beta_v,
                           const float* __restrict__ beta_a,
                           const float* __restrict__ lam,
                           float* __restrict__ mu_out, float* __restrict__ T_out,
                           float* __restrict__ out) {
  const int t = threadIdx.x;
  if (t >= 64) return;
  const int b = t >> 4, c = t & 15;
  const float* S1 = Sred;
  const float* S2 = Sred + SLAB;
  const float sr = Sred[2 * SLAB + b * CC + c];
  const float inv = 1.f / sr;
  const float bv = beta_v[0];
  float csum = 0.f, lsum = 0.f;
  for (int l = 0; l < LV; l++) {
    const int idx = (b * CC + c) * LV + l;
    const float m = S1[idx] * inv;
    float s2 = S2[idx] * inv - m * m;
    s2 = fmaxf(s2, 0.01f);
    const float ls = logf(s2);
    csum += bv + ls;
    lsum += ls;
    if (FINAL) out[(size_t)b * 1040 + c * LV + l] = m;
    else mu_out[idx] = m;
  }
  const float z = lam[0] * (beta_a[c] - csum * sr);
  const float ac = 1.f / (1.f + expf(-z));
  if (FINAL) out[(size_t)b * 1040 + 1024 + c] = ac;
  else T_out[b * CC + c] = logf(ac) - 0.5f * (64.f * LOG_2PI_F + lsum);
}

extern "C" void kernel_launch(void* const* d_in, const int* in_sizes, int n_in,
                              void* d_out, int out_size, void* d_ws, size_t ws_size,
                              hipStream_t stream) {
  const float* x = (const float*)d_in[0];
  const float* W = (const float*)d_in[1];
  const float* beta_v = (const float*)d_in[2];
  const float* beta_a = (const float*)d_in[3];
  const float* lam = (const float*)d_in[4];
  float* out = (float*)d_out;

  const size_t need = ((size_t)BC * SLABTOT + SLABTOT + SLAB + 64) * sizeof(float);
  const int nslab = (ws_size >= need) ? BC : NSLAB_SM;
  const bool store = (nslab == BC);

  float* Spart = (float*)d_ws;
  float* Sred = Spart + (size_t)nslab * SLABTOT;
  float* muW = Sred + SLABTOT;
  float* Tw = muW + SLAB;

  const int chunk = 32;
  const dim3 rgrid((SLABTOT + 255) / 256, (nslab + chunk - 1) / chunk);

  // ---- pass 0 ----
  if (!store) hipMemsetAsync(Spart, 0, (size_t)nslab * SLABTOT * sizeof(float), stream);
  hipMemsetAsync(Sred, 0, SLABTOT * sizeof(float), stream);
  if (store) em_sweep<0, 1><<<dim3(BC), dim3(512), 0, stream>>>(x, W, nullptr, nullptr, Spart, nslab);
  else       em_sweep<0, 0><<<dim3(BC), dim3(512), 0, stream>>>(x, W, nullptr, nullptr, Spart, nslab);
  reduce_slabs<<<rgrid, dim3(256), 0, stream>>>(Spart, Sred, nslab, chunk);
  stats_post<0><<<dim3(1), dim3(64), 0, stream>>>(Sred, beta_v, beta_a, lam, muW, Tw, nullptr);

  // ---- pass 1 ----
  if (!store) hipMemsetAsync(Spart, 0, (size_t)nslab * SLABTOT * sizeof(float), stream);
  hipMemsetAsync(Sred, 0, SLABTOT * sizeof(float), stream);
  if (store) em_sweep<1, 1><<<dim3(BC), dim3(512), 0, stream>>>(x, W, muW, Tw, Spart, nslab);
  else       em_sweep<1, 0><<<dim3(BC), dim3(512), 0, stream>>>(x, W, muW, Tw, Spart, nslab);
  reduce_slabs<<<rgrid, dim3(256), 0, stream>>>(Spart, Sred, nslab, chunk);
  stats_post<1><<<dim3(1), dim3(64), 0, stream>>>(Sred, beta_v, beta_a, lam, nullptr, nullptr, out);
}